// Round 11
// baseline (2324.407 us; speedup 1.0000x reference)
//
#include <hip/hip_runtime.h>
#include <hip/hip_bf16.h>
#include <math.h>

// Problem constants
#define BQ   16384        // windows
#define CH   512
#define NH   8
#define HID  2048
#define NTOK (BQ*4)       // 65536 rows

using bf16 = __hip_bfloat16;
typedef __bf16 bf16x8 __attribute__((ext_vector_type(8)));
typedef float  f32x4  __attribute__((ext_vector_type(4)));

#define FENCE() asm volatile("" ::: "memory")

__device__ __forceinline__ void gload16(const void* g, void* l) {
    __builtin_amdgcn_global_load_lds(
        (const __attribute__((address_space(1))) void*)g,
        (__attribute__((address_space(3))) void*)l, 16, 0, 0);
}

// ---------------- weight pack B: fp32 [N][K] -> per-wave coalesced frag order --
// Slab per (cb = col/128, s32 = k/32): 4096 elems (8KB), layout
//   [ntile 0..7][lane 0..63]x(16B):  elem addr = (cb*NSk32 + s32)*4096 + nt*512 + l*8
//   content = W[cb*128 + nt*16 + (l&15)][s32*32 + (l>>4)*8 .. +8]
// A wave (wch) reads ntiles wch*4..+3 as 4 contiguous 1KB global_load_dwordx4
// per K-32 -> B operand fragments land in registers exactly in MFMA layout.
__global__ __launch_bounds__(256) void packb(const float* __restrict__ Wsrc,
                                             bf16* __restrict__ out, int N, int K) {
    int q = blockIdx.x * 256 + threadIdx.x;      // 16B-chunk id
    int NSk32 = K >> 5;
    int total = (N >> 7) * NSk32 * 512;
    if (q >= total) return;
    int l   = q & 63;
    int nt  = (q >> 6) & 7;
    int s32 = (q >> 9) % NSk32;
    int cb  = q / (NSk32 * 512);
    int row = cb * 128 + nt * 16 + (l & 15);
    int k   = s32 * 32 + (l >> 4) * 8;
    const float* src = Wsrc + (size_t)row * K + k;
    float4 v0 = *(const float4*)src;
    float4 v1 = *(const float4*)(src + 4);
    __align__(16) bf16 t[8];
    t[0] = __float2bfloat16(v0.x); t[1] = __float2bfloat16(v0.y);
    t[2] = __float2bfloat16(v0.z); t[3] = __float2bfloat16(v0.w);
    t[4] = __float2bfloat16(v1.x); t[5] = __float2bfloat16(v1.y);
    t[6] = __float2bfloat16(v1.z); t[7] = __float2bfloat16(v1.w);
    *(uint4*)&out[(size_t)q * 8] = *(const uint4*)t;
}

// ---------------- LayerNorm (fp32 in, bf16 out), one wave per row ----------------
__global__ __launch_bounds__(256) void ln_kernel(const float* __restrict__ x,
                                                 const float* __restrict__ g,
                                                 const float* __restrict__ b,
                                                 bf16* __restrict__ out) {
    int row  = blockIdx.x * 4 + (threadIdx.x >> 6);
    int lane = threadIdx.x & 63;
    const float* xr = x + (size_t)row * CH;
    int c0 = lane * 8;
    float4 v0 = *(const float4*)&xr[c0];
    float4 v1 = *(const float4*)&xr[c0 + 4];
    float s  = v0.x + v0.y + v0.z + v0.w + v1.x + v1.y + v1.z + v1.w;
    float sq = v0.x*v0.x + v0.y*v0.y + v0.z*v0.z + v0.w*v0.w
             + v1.x*v1.x + v1.y*v1.y + v1.z*v1.z + v1.w*v1.w;
#pragma unroll
    for (int off = 32; off >= 1; off >>= 1) {
        s  += __shfl_xor(s,  off, 64);
        sq += __shfl_xor(sq, off, 64);
    }
    float mu  = s * (1.0f / CH);
    float var = sq * (1.0f / CH) - mu * mu;
    float rs  = rsqrtf(var + 1e-5f);
    float4 g0 = *(const float4*)&g[c0];
    float4 g1 = *(const float4*)&g[c0 + 4];
    float4 b0 = *(const float4*)&b[c0];
    float4 b1 = *(const float4*)&b[c0 + 4];
    __align__(16) bf16 t[8];
    t[0] = __float2bfloat16((v0.x - mu) * rs * g0.x + b0.x);
    t[1] = __float2bfloat16((v0.y - mu) * rs * g0.y + b0.y);
    t[2] = __float2bfloat16((v0.z - mu) * rs * g0.z + b0.z);
    t[3] = __float2bfloat16((v0.w - mu) * rs * g0.w + b0.w);
    t[4] = __float2bfloat16((v1.x - mu) * rs * g1.x + b1.x);
    t[5] = __float2bfloat16((v1.y - mu) * rs * g1.y + b1.y);
    t[6] = __float2bfloat16((v1.z - mu) * rs * g1.z + b1.z);
    t[7] = __float2bfloat16((v1.w - mu) * rs * g1.w + b1.w);
    *(uint4*)&out[(size_t)row * CH + c0] = *(const uint4*)t;
}

// ---------------- GEMM 128x128, BK=64, A-in-LDS ring-2, B direct to registers ---
// C[M,N] = A[M,K] * B[N,K]^T, 4 waves (2x2), wave tile 64x64.
// Per BK-64 slice: A staged to LDS (16KB: 2 K32-halves x [128rows][64B] XOR
// layout, 4 gload_lds/thread); B fragments loaded straight from packed global
// (L2-resident panels) into double-banked registers bvA/bvB (8 x 1KB coalesced
// loads/wave). Loop: { stageA(s+1); loadB(s+1); vmcnt(12); barrier;
// compute(8 ds_read + 32 MFMA); barrier }.
//  RAW: vmcnt(12) retires slice s's 4 A-gloads + 8 B-loads (12 outstanding =
//       slice s+1's); barrier globalizes the LDS image.
//  WAR: trailing barrier keeps slot s&1 readers ahead of stageA(s+2).
// vs R10: half the syncs per K, half the LDS traffic per FLOP (B removed),
// same 32KB LDS -> 4+ blocks/CU.
// EPI 0: outB = bf16(acc); EPI 1: outF = acc+bias+resid; EPI 2: gelu -> outB.
template<int EPI>
__global__ __launch_bounds__(256, 4)
void gemmk64(const bf16* __restrict__ A, const bf16* __restrict__ Bp,
             int M, int N, int K, int nbx,
             const float* __restrict__ bias,
             const float* resid, float* outF, bf16* __restrict__ outB) {
    __shared__ __align__(16) char lds[32768];
    const int tid  = threadIdx.x;
    const int w    = tid >> 6;     // wave 0..3
    const int lane = tid & 63;

    // bijective XCD swizzle (gridDim.x % 8 == 0 for all our shapes)
    const int nb  = gridDim.x;
    const int id  = blockIdx.x;
    const int swz = (id & 7) * (nb >> 3) + (id >> 3);
    const int bx  = swz % nbx, by = swz / nbx;
    const int bm = by * 128, bn = bx * 128;
    const int wrh = w >> 1;        // 0..1  (M half)
    const int wch = w & 1;         // 0..1  (N half)
    const int NS    = K >> 6;      // BK-64 slices (8 or 32; even)
    const int NSk32 = K >> 5;

    // A staging (strided rows, pre-swizzled k-part; two K32-halves per slice)
    const int rl  = lane >> 2;
    const int kpe = ((lane & 3) ^ ((lane >> 3) & 3)) * 8;
    const bf16* gA0 = A + (size_t)(bm + w * 32 + rl) * K + kpe;
    const bf16* gA1 = gA0 + (size_t)16 * K;
    // B packed base for this wave (ntiles wch*4..+3)
    const bf16* gB = Bp + (size_t)(bn >> 7) * NSk32 * 4096 + (wch * 4) * 512 + lane * 8;

    // A fragment read offset within an 8KB K32-half (XOR slot, conflict-free)
    const int kslot = ((lane >> 4) ^ ((lane >> 1) & 3));
    const int aoff = (wrh * 64 + (lane & 15)) * 64 + kslot * 16;

    f32x4 acc[4][4] = {};
    bf16x8 bvA[8], bvB[8];         // B frag banks: [kh*4 + n]

    auto stageA = [&](int s) {
        char* base = (char*)lds + (s & 1) * 16384;
        gload16(gA0 + (size_t)s * 64,      base + w * 2048);
        gload16(gA1 + (size_t)s * 64,      base + w * 2048 + 1024);
        gload16(gA0 + (size_t)s * 64 + 32, base + 8192 + w * 2048);
        gload16(gA1 + (size_t)s * 64 + 32, base + 8192 + w * 2048 + 1024);
    };

#define LOADB(BV, S) {                                                       \
    const bf16* _p = gB + (size_t)(2 * (S)) * 4096;                          \
    BV[0] = *(const bf16x8*)(_p);        BV[1] = *(const bf16x8*)(_p + 512); \
    BV[2] = *(const bf16x8*)(_p + 1024); BV[3] = *(const bf16x8*)(_p + 1536);\
    BV[4] = *(const bf16x8*)(_p + 4096);        BV[5] = *(const bf16x8*)(_p + 4096 + 512); \
    BV[6] = *(const bf16x8*)(_p + 4096 + 1024); BV[7] = *(const bf16x8*)(_p + 4096 + 1536); }

#define COMPUTE(SLOT, BV) {                                                  \
    const char* _b = (const char*)lds + (size_t)(SLOT) * 16384;              \
    bf16x8 _av0[4], _av1[4];                                                 \
    _Pragma("unroll") for (int _m = 0; _m < 4; ++_m) {                       \
        _av0[_m] = *(const bf16x8*)(_b + aoff + _m * 1024);                  \
        _av1[_m] = *(const bf16x8*)(_b + 8192 + aoff + _m * 1024); }         \
    _Pragma("unroll") for (int _m = 0; _m < 4; ++_m)                         \
    _Pragma("unroll") for (int _n = 0; _n < 4; ++_n)                         \
        acc[_m][_n] = __builtin_amdgcn_mfma_f32_16x16x32_bf16(_av0[_m], BV[_n], acc[_m][_n], 0, 0, 0); \
    _Pragma("unroll") for (int _m = 0; _m < 4; ++_m)                         \
    _Pragma("unroll") for (int _n = 0; _n < 4; ++_n)                         \
        acc[_m][_n] = __builtin_amdgcn_mfma_f32_16x16x32_bf16(_av1[_m], BV[4 + _n], acc[_m][_n], 0, 0, 0); }

#define WAITV(n) asm volatile("s_waitcnt vmcnt(" #n ")" ::: "memory")
#define SBAR()   __builtin_amdgcn_s_barrier()

    stageA(0); LOADB(bvA, 0);
    for (int s = 0; s < NS - 2; s += 2) {
        stageA(s + 1); LOADB(bvB, s + 1);
        WAITV(12); SBAR(); FENCE();
        COMPUTE(s & 1, bvA);
        FENCE(); SBAR();
        stageA(s + 2); LOADB(bvA, s + 2);
        WAITV(12); SBAR(); FENCE();
        COMPUTE((s + 1) & 1, bvB);
        FENCE(); SBAR();
    }
    // s = NS-2 (even): prefetch last slice into bvB
    stageA(NS - 1); LOADB(bvB, NS - 1);
    WAITV(12); SBAR(); FENCE();
    COMPUTE((NS - 2) & 1, bvA);
    FENCE(); SBAR();
    WAITV(0); SBAR(); FENCE();
    COMPUTE((NS - 1) & 1, bvB);
#undef LOADB
#undef COMPUTE
#undef WAITV
#undef SBAR

    // epilogue: frag (m,n): row = wrh*64 + m*16 + (lane>>4)*4 + r, col = wch*64 + n*16 + (lane&15)
    const int erow0 = bm + wrh * 64 + (lane >> 4) * 4;
    const int ecol0 = bn + wch * 64 + (lane & 15);
#pragma unroll
    for (int m = 0; m < 4; ++m) {
#pragma unroll
        for (int n = 0; n < 4; ++n) {
            int col = ecol0 + n * 16;
#pragma unroll
            for (int r = 0; r < 4; ++r) {
                int row = erow0 + m * 16 + r;
                size_t idx = (size_t)row * N + col;
                float v = acc[m][n][r];
                if (EPI == 0) {
                    outB[idx] = __float2bfloat16(v);
                } else if (EPI == 1) {
                    outF[idx] = v + bias[col] + resid[idx];
                } else {
                    // tanh-form GELU (|err| vs exact erf-GELU ~3e-4 << bf16 ulp)
                    float t = v + bias[col];
                    float u = 0.7978845608f * t * (1.0f + 0.044715f * t * t);
                    float e = __expf(2.0f * u);
                    float th = 1.0f - 2.0f / (e + 1.0f);   // inf-safe
                    outB[idx] = __float2bfloat16(0.5f * t * (1.0f + th));
                }
            }
        }
    }
}

// ---------------- windowed attention: one block per window ----------------
__global__ __launch_bounds__(256)
void attn_kernel(const bf16* __restrict__ qkv, const float* __restrict__ rpb,
                 bf16* __restrict__ o) {
    __shared__ __align__(16) bf16 sT[4 * 1536];
    __shared__ float sS[NH][4][4];
    __shared__ float sP[NH][4][4];
    int b   = blockIdx.x;
    int tid = threadIdx.x;
    const bf16* src = qkv + (size_t)b * (4 * 1536);
#pragma unroll
    for (int it = 0; it < 3; ++it) {
        int e = (it * 256 + tid) * 8;
        *(uint4*)&sT[e] = *(const uint4*)&src[e];
    }
    __syncthreads();
    if (tid < 128) {
        int h = tid >> 4, i = (tid >> 2) & 3, j = tid & 3;
        const bf16* q = &sT[i * 1536 + h * 64];
        const bf16* k = &sT[j * 1536 + 512 + h * 64];
        float acc = 0.f;
#pragma unroll
        for (int d = 0; d < 64; ++d)
            acc += __bfloat162float(q[d]) * __bfloat162float(k[d]);
        int rel = (((i >> 1) - (j >> 1)) + 1) * 3 + (((i & 1) - (j & 1)) + 1);
        sS[h][i][j] = acc * 0.125f + rpb[rel * NH + h];
    }
    __syncthreads();
    if (tid < 32) {
        int h = tid >> 2, i = tid & 3;
        float s0 = sS[h][i][0], s1 = sS[h][i][1], s2 = sS[h][i][2], s3 = sS[h][i][3];
        float mx = fmaxf(fmaxf(s0, s1), fmaxf(s2, s3));
        float e0 = expf(s0 - mx), e1 = expf(s1 - mx), e2 = expf(s2 - mx), e3 = expf(s3 - mx);
        float inv = 1.f / (e0 + e1 + e2 + e3);
        sP[h][i][0] = e0 * inv; sP[h][i][1] = e1 * inv;
        sP[h][i][2] = e2 * inv; sP[h][i][3] = e3 * inv;
    }
    __syncthreads();
    {
        int h = tid >> 5, tl = tid & 31;
        int d = tl * 2;
        const bf16* v = &sT[1024 + h * 64 + d];
#pragma unroll
        for (int i = 0; i < 4; ++i) {
            float p0 = sP[h][i][0], p1 = sP[h][i][1], p2 = sP[h][i][2], p3 = sP[h][i][3];
            float o0 = p0 * __bfloat162float(v[0])        + p1 * __bfloat162float(v[1536])
                     + p2 * __bfloat162float(v[2 * 1536]) + p3 * __bfloat162float(v[3 * 1536]);
            float o1 = p0 * __bfloat162float(v[1])            + p1 * __bfloat162float(v[1536 + 1])
                     + p2 * __bfloat162float(v[2 * 1536 + 1]) + p3 * __bfloat162float(v[3 * 1536 + 1]);
            __hip_bfloat162 pr;
            pr.x = __float2bfloat16(o0);
            pr.y = __float2bfloat16(o1);
            *(__hip_bfloat162*)&o[(size_t)(b * 4 + i) * CH + h * 64 + d] = pr;
        }
    }
}

extern "C" void kernel_launch(void* const* d_in, const int* in_sizes, int n_in,
                              void* d_out, int out_size, void* d_ws, size_t ws_size,
                              hipStream_t stream) {
    const float* x      = (const float*)d_in[0];
    const float* ln_g   = (const float*)d_in[1];
    const float* ln_b   = (const float*)d_in[2];
    const float* qkv_w  = (const float*)d_in[3];
    const float* proj_w = (const float*)d_in[4];
    const float* proj_b = (const float*)d_in[5];
    const float* rpb    = (const float*)d_in[6];
    const float* fc1_w  = (const float*)d_in[7];
    const float* fc1_b  = (const float*)d_in[8];
    const float* fc2_w  = (const float*)d_in[9];
    const float* fc2_b  = (const float*)d_in[10];
    float* out = (float*)d_out;

    // workspace layout (16B aligned throughout)
    char* ws = (char*)d_ws;
    bf16* wQKV  = (bf16*)ws;  ws += (size_t)1536 * 512 * 2;   // packed
    bf16* wPROJ = (bf16*)ws;  ws += (size_t)512  * 512 * 2;
    bf16* wFC1  = (bf16*)ws;  ws += (size_t)2048 * 512 * 2;
    bf16* wFC2  = (bf16*)ws;  ws += (size_t)512 * 2048 * 2;
    bf16* hA    = (bf16*)ws;  ws += (size_t)NTOK * 512 * 2;   // 64 MB: h_ln -> o -> h2
    bf16* big   = (bf16*)ws;                                  // 256 MB: qkv -> fc1 out
    const size_t needed = 6291456ull + 67108864ull + 268435456ull;
    if (ws_size < needed) return;

    // weight packing (fp32 -> frag-order bf16 slabs)
    packb<<<384, 256, 0, stream>>>(qkv_w,  wQKV, 1536, 512);
    packb<<<128, 256, 0, stream>>>(proj_w, wPROJ, 512, 512);
    packb<<<512, 256, 0, stream>>>(fc1_w,  wFC1, 2048, 512);
    packb<<<512, 256, 0, stream>>>(fc2_w,  wFC2, 512, 2048);

    // LN1: x -> hA (bf16)
    ln_kernel<<<NTOK / 4, 256, 0, stream>>>(x, ln_g, ln_b, hA);
    // qkv = hA @ qkv_w^T  -> big
    gemmk64<0><<<dim3(12 * 512), 256, 0, stream>>>(
        hA, wQKV, NTOK, 1536, 512, 12, nullptr, nullptr, nullptr, big);
    // attention: big -> hA (o)
    attn_kernel<<<BQ, 256, 0, stream>>>(big, rpb, hA);
    // x1 = x + o @ proj_w^T + proj_b -> out (fp32)
    gemmk64<1><<<dim3(4 * 512), 256, 0, stream>>>(
        hA, wPROJ, NTOK, 512, 512, 4, proj_b, x, out, nullptr);
    // LN2: out -> hA (h2)
    ln_kernel<<<NTOK / 4, 256, 0, stream>>>(out, ln_g, ln_b, hA);
    // g = gelu(h2 @ fc1_w^T + fc1_b) -> big (bf16)
    gemmk64<2><<<dim3(16 * 512), 256, 0, stream>>>(
        hA, wFC1, NTOK, 2048, 512, 16, fc1_b, nullptr, nullptr, big);
    // out = x1 + g @ fc2_w^T + fc2_b (in-place residual read)
    gemmk64<1><<<dim3(4 * 512), 256, 0, stream>>>(
        big, wFC2, NTOK, 512, 2048, 4, fc2_b, out, out, nullptr);
}

// Round 12
// 877.954 us; speedup vs baseline: 2.6475x; 2.6475x over previous
//
#include <hip/hip_runtime.h>
#include <hip/hip_bf16.h>
#include <math.h>

// Problem constants
#define BQ   16384        // windows
#define CH   512
#define NH   8
#define HID  2048
#define NTOK (BQ*4)       // 65536 rows

using bf16 = __hip_bfloat16;
typedef __bf16 bf16x8 __attribute__((ext_vector_type(8)));
typedef float  f32x4  __attribute__((ext_vector_type(4)));

#define FENCE() asm volatile("" ::: "memory")

__device__ __forceinline__ void gload16(const void* g, void* l) {
    __builtin_amdgcn_global_load_lds(
        (const __attribute__((address_space(1))) void*)g,
        (__attribute__((address_space(3))) void*)l, 16, 0, 0);
}

// ---------------- weight pack B: fp32 [N][K] -> per-wave coalesced frag order --
// Slab per (cb = col/128, s32 = k/32): 4096 elems (8KB), layout
//   [ntile 0..7][lane 0..63]x(16B):  elem addr = (cb*NSk32 + s32)*4096 + nt*512 + l*8
//   content = W[cb*128 + nt*16 + (l&15)][s32*32 + (l>>4)*8 .. +8]
__global__ __launch_bounds__(256) void packb(const float* __restrict__ Wsrc,
                                             bf16* __restrict__ out, int N, int K) {
    int q = blockIdx.x * 256 + threadIdx.x;      // 16B-chunk id
    int NSk32 = K >> 5;
    int total = (N >> 7) * NSk32 * 512;
    if (q >= total) return;
    int l   = q & 63;
    int nt  = (q >> 6) & 7;
    int s32 = (q >> 9) % NSk32;
    int cb  = q / (NSk32 * 512);
    int row = cb * 128 + nt * 16 + (l & 15);
    int k   = s32 * 32 + (l >> 4) * 8;
    const float* src = Wsrc + (size_t)row * K + k;
    float4 v0 = *(const float4*)src;
    float4 v1 = *(const float4*)(src + 4);
    __align__(16) bf16 t[8];
    t[0] = __float2bfloat16(v0.x); t[1] = __float2bfloat16(v0.y);
    t[2] = __float2bfloat16(v0.z); t[3] = __float2bfloat16(v0.w);
    t[4] = __float2bfloat16(v1.x); t[5] = __float2bfloat16(v1.y);
    t[6] = __float2bfloat16(v1.z); t[7] = __float2bfloat16(v1.w);
    *(uint4*)&out[(size_t)q * 8] = *(const uint4*)t;
}

// ---------------- LayerNorm (fp32 in, bf16 out), one wave per row ----------------
__global__ __launch_bounds__(256) void ln_kernel(const float* __restrict__ x,
                                                 const float* __restrict__ g,
                                                 const float* __restrict__ b,
                                                 bf16* __restrict__ out) {
    int row  = blockIdx.x * 4 + (threadIdx.x >> 6);
    int lane = threadIdx.x & 63;
    const float* xr = x + (size_t)row * CH;
    int c0 = lane * 8;
    float4 v0 = *(const float4*)&xr[c0];
    float4 v1 = *(const float4*)&xr[c0 + 4];
    float s  = v0.x + v0.y + v0.z + v0.w + v1.x + v1.y + v1.z + v1.w;
    float sq = v0.x*v0.x + v0.y*v0.y + v0.z*v0.z + v0.w*v0.w
             + v1.x*v1.x + v1.y*v1.y + v1.z*v1.z + v1.w*v1.w;
#pragma unroll
    for (int off = 32; off >= 1; off >>= 1) {
        s  += __shfl_xor(s,  off, 64);
        sq += __shfl_xor(sq, off, 64);
    }
    float mu  = s * (1.0f / CH);
    float var = sq * (1.0f / CH) - mu * mu;
    float rs  = rsqrtf(var + 1e-5f);
    float4 g0 = *(const float4*)&g[c0];
    float4 g1 = *(const float4*)&g[c0 + 4];
    float4 b0 = *(const float4*)&b[c0];
    float4 b1 = *(const float4*)&b[c0 + 4];
    __align__(16) bf16 t[8];
    t[0] = __float2bfloat16((v0.x - mu) * rs * g0.x + b0.x);
    t[1] = __float2bfloat16((v0.y - mu) * rs * g0.y + b0.y);
    t[2] = __float2bfloat16((v0.z - mu) * rs * g0.z + b0.z);
    t[3] = __float2bfloat16((v0.w - mu) * rs * g0.w + b0.w);
    t[4] = __float2bfloat16((v1.x - mu) * rs * g1.x + b1.x);
    t[5] = __float2bfloat16((v1.y - mu) * rs * g1.y + b1.y);
    t[6] = __float2bfloat16((v1.z - mu) * rs * g1.z + b1.z);
    t[7] = __float2bfloat16((v1.w - mu) * rs * g1.w + b1.w);
    *(uint4*)&out[(size_t)row * CH + c0] = *(const uint4*)t;
}

// ---------------- GEMM 128x128, BK=64, A-in-LDS ring-2, B direct to registers ---
// Identical to round 11 EXCEPT __launch_bounds__(256,3): R11's (256,4) capped
// VGPRs at 128 while the B register banks (bvA/bvB = 64 VGPR) push the live set
// to ~156 -> total spill (VGPR_Count 64, 1.76GB scratch writes/dispatch, 6.6%
// MfmaUtil). (256,3) caps at ~170 -> fits, no spill, ~3 blocks/CU.
// B never touches LDS: LDS traffic per FLOP halves, and the barrier-bracketed
// critical path holds only the 8 A ds_reads; B loads pipeline freely in VMEM.
template<int EPI>
__global__ __launch_bounds__(256, 3)
void gemmk64(const bf16* __restrict__ A, const bf16* __restrict__ Bp,
             int M, int N, int K, int nbx,
             const float* __restrict__ bias,
             const float* resid, float* outF, bf16* __restrict__ outB) {
    __shared__ __align__(16) char lds[32768];
    const int tid  = threadIdx.x;
    const int w    = tid >> 6;     // wave 0..3
    const int lane = tid & 63;

    // bijective XCD swizzle (gridDim.x % 8 == 0 for all our shapes)
    const int nb  = gridDim.x;
    const int id  = blockIdx.x;
    const int swz = (id & 7) * (nb >> 3) + (id >> 3);
    const int bx  = swz % nbx, by = swz / nbx;
    const int bm = by * 128, bn = bx * 128;
    const int wrh = w >> 1;        // 0..1  (M half)
    const int wch = w & 1;         // 0..1  (N half)
    const int NS    = K >> 6;      // BK-64 slices (8 or 32; even)
    const int NSk32 = K >> 5;

    // A staging (strided rows, pre-swizzled k-part; two K32-halves per slice)
    const int rl  = lane >> 2;
    const int kpe = ((lane & 3) ^ ((lane >> 3) & 3)) * 8;
    const bf16* gA0 = A + (size_t)(bm + w * 32 + rl) * K + kpe;
    const bf16* gA1 = gA0 + (size_t)16 * K;
    // B packed base for this wave (ntiles wch*4..+3)
    const bf16* gB = Bp + (size_t)(bn >> 7) * NSk32 * 4096 + (wch * 4) * 512 + lane * 8;

    // A fragment read offset within an 8KB K32-half (XOR slot, conflict-free)
    const int kslot = ((lane >> 4) ^ ((lane >> 1) & 3));
    const int aoff = (wrh * 64 + (lane & 15)) * 64 + kslot * 16;

    f32x4 acc[4][4] = {};
    bf16x8 bvA[8], bvB[8];         // B frag banks: [kh*4 + n]

    auto stageA = [&](int s) {
        char* base = (char*)lds + (s & 1) * 16384;
        gload16(gA0 + (size_t)s * 64,      base + w * 2048);
        gload16(gA1 + (size_t)s * 64,      base + w * 2048 + 1024);
        gload16(gA0 + (size_t)s * 64 + 32, base + 8192 + w * 2048);
        gload16(gA1 + (size_t)s * 64 + 32, base + 8192 + w * 2048 + 1024);
    };

#define LOADB(BV, S) {                                                       \
    const bf16* _p = gB + (size_t)(2 * (S)) * 4096;                          \
    BV[0] = *(const bf16x8*)(_p);        BV[1] = *(const bf16x8*)(_p + 512); \
    BV[2] = *(const bf16x8*)(_p + 1024); BV[3] = *(const bf16x8*)(_p + 1536);\
    BV[4] = *(const bf16x8*)(_p + 4096);        BV[5] = *(const bf16x8*)(_p + 4096 + 512); \
    BV[6] = *(const bf16x8*)(_p + 4096 + 1024); BV[7] = *(const bf16x8*)(_p + 4096 + 1536); }

#define COMPUTE(SLOT, BV) {                                                  \
    const char* _b = (const char*)lds + (size_t)(SLOT) * 16384;              \
    bf16x8 _av0[4], _av1[4];                                                 \
    _Pragma("unroll") for (int _m = 0; _m < 4; ++_m) {                       \
        _av0[_m] = *(const bf16x8*)(_b + aoff + _m * 1024);                  \
        _av1[_m] = *(const bf16x8*)(_b + 8192 + aoff + _m * 1024); }         \
    _Pragma("unroll") for (int _m = 0; _m < 4; ++_m)                         \
    _Pragma("unroll") for (int _n = 0; _n < 4; ++_n)                         \
        acc[_m][_n] = __builtin_amdgcn_mfma_f32_16x16x32_bf16(_av0[_m], BV[_n], acc[_m][_n], 0, 0, 0); \
    _Pragma("unroll") for (int _m = 0; _m < 4; ++_m)                         \
    _Pragma("unroll") for (int _n = 0; _n < 4; ++_n)                         \
        acc[_m][_n] = __builtin_amdgcn_mfma_f32_16x16x32_bf16(_av1[_m], BV[4 + _n], acc[_m][_n], 0, 0, 0); }

#define WAITV(n) asm volatile("s_waitcnt vmcnt(" #n ")" ::: "memory")
#define SBAR()   __builtin_amdgcn_s_barrier()

    stageA(0); LOADB(bvA, 0);
    for (int s = 0; s < NS - 2; s += 2) {
        stageA(s + 1); LOADB(bvB, s + 1);
        WAITV(12); SBAR(); FENCE();
        COMPUTE(s & 1, bvA);
        FENCE(); SBAR();
        stageA(s + 2); LOADB(bvA, s + 2);
        WAITV(12); SBAR(); FENCE();
        COMPUTE((s + 1) & 1, bvB);
        FENCE(); SBAR();
    }
    // s = NS-2 (even): prefetch last slice into bvB
    stageA(NS - 1); LOADB(bvB, NS - 1);
    WAITV(12); SBAR(); FENCE();
    COMPUTE((NS - 2) & 1, bvA);
    FENCE(); SBAR();
    WAITV(0); SBAR(); FENCE();
    COMPUTE((NS - 1) & 1, bvB);
#undef LOADB
#undef COMPUTE
#undef WAITV
#undef SBAR

    // epilogue: frag (m,n): row = wrh*64 + m*16 + (lane>>4)*4 + r, col = wch*64 + n*16 + (lane&15)
    const int erow0 = bm + wrh * 64 + (lane >> 4) * 4;
    const int ecol0 = bn + wch * 64 + (lane & 15);
#pragma unroll
    for (int m = 0; m < 4; ++m) {
#pragma unroll
        for (int n = 0; n < 4; ++n) {
            int col = ecol0 + n * 16;
#pragma unroll
            for (int r = 0; r < 4; ++r) {
                int row = erow0 + m * 16 + r;
                size_t idx = (size_t)row * N + col;
                float v = acc[m][n][r];
                if (EPI == 0) {
                    outB[idx] = __float2bfloat16(v);
                } else if (EPI == 1) {
                    outF[idx] = v + bias[col] + resid[idx];
                } else {
                    // tanh-form GELU (|err| vs exact erf-GELU ~3e-4 << bf16 ulp)
                    float t = v + bias[col];
                    float u = 0.7978845608f * t * (1.0f + 0.044715f * t * t);
                    float e = __expf(2.0f * u);
                    float th = 1.0f - 2.0f / (e + 1.0f);   // inf-safe
                    outB[idx] = __float2bfloat16(0.5f * t * (1.0f + th));
                }
            }
        }
    }
}

// ---------------- windowed attention: one block per window ----------------
__global__ __launch_bounds__(256)
void attn_kernel(const bf16* __restrict__ qkv, const float* __restrict__ rpb,
                 bf16* __restrict__ o) {
    __shared__ __align__(16) bf16 sT[4 * 1536];
    __shared__ float sS[NH][4][4];
    __shared__ float sP[NH][4][4];
    int b   = blockIdx.x;
    int tid = threadIdx.x;
    const bf16* src = qkv + (size_t)b * (4 * 1536);
#pragma unroll
    for (int it = 0; it < 3; ++it) {
        int e = (it * 256 + tid) * 8;
        *(uint4*)&sT[e] = *(const uint4*)&src[e];
    }
    __syncthreads();
    if (tid < 128) {
        int h = tid >> 4, i = (tid >> 2) & 3, j = tid & 3;
        const bf16* q = &sT[i * 1536 + h * 64];
        const bf16* k = &sT[j * 1536 + 512 + h * 64];
        float acc = 0.f;
#pragma unroll
        for (int d = 0; d < 64; ++d)
            acc += __bfloat162float(q[d]) * __bfloat162float(k[d]);
        int rel = (((i >> 1) - (j >> 1)) + 1) * 3 + (((i & 1) - (j & 1)) + 1);
        sS[h][i][j] = acc * 0.125f + rpb[rel * NH + h];
    }
    __syncthreads();
    if (tid < 32) {
        int h = tid >> 2, i = tid & 3;
        float s0 = sS[h][i][0], s1 = sS[h][i][1], s2 = sS[h][i][2], s3 = sS[h][i][3];
        float mx = fmaxf(fmaxf(s0, s1), fmaxf(s2, s3));
        float e0 = expf(s0 - mx), e1 = expf(s1 - mx), e2 = expf(s2 - mx), e3 = expf(s3 - mx);
        float inv = 1.f / (e0 + e1 + e2 + e3);
        sP[h][i][0] = e0 * inv; sP[h][i][1] = e1 * inv;
        sP[h][i][2] = e2 * inv; sP[h][i][3] = e3 * inv;
    }
    __syncthreads();
    {
        int h = tid >> 5, tl = tid & 31;
        int d = tl * 2;
        const bf16* v = &sT[1024 + h * 64 + d];
#pragma unroll
        for (int i = 0; i < 4; ++i) {
            float p0 = sP[h][i][0], p1 = sP[h][i][1], p2 = sP[h][i][2], p3 = sP[h][i][3];
            float o0 = p0 * __bfloat162float(v[0])        + p1 * __bfloat162float(v[1536])
                     + p2 * __bfloat162float(v[2 * 1536]) + p3 * __bfloat162float(v[3 * 1536]);
            float o1 = p0 * __bfloat162float(v[1])            + p1 * __bfloat162float(v[1536 + 1])
                     + p2 * __bfloat162float(v[2 * 1536 + 1]) + p3 * __bfloat162float(v[3 * 1536 + 1]);
            __hip_bfloat162 pr;
            pr.x = __float2bfloat16(o0);
            pr.y = __float2bfloat16(o1);
            *(__hip_bfloat162*)&o[(size_t)(b * 4 + i) * CH + h * 64 + d] = pr;
        }
    }
}

extern "C" void kernel_launch(void* const* d_in, const int* in_sizes, int n_in,
                              void* d_out, int out_size, void* d_ws, size_t ws_size,
                              hipStream_t stream) {
    const float* x      = (const float*)d_in[0];
    const float* ln_g   = (const float*)d_in[1];
    const float* ln_b   = (const float*)d_in[2];
    const float* qkv_w  = (const float*)d_in[3];
    const float* proj_w = (const float*)d_in[4];
    const float* proj_b = (const float*)d_in[5];
    const float* rpb    = (const float*)d_in[6];
    const float* fc1_w  = (const float*)d_in[7];
    const float* fc1_b  = (const float*)d_in[8];
    const float* fc2_w  = (const float*)d_in[9];
    const float* fc2_b  = (const float*)d_in[10];
    float* out = (float*)d_out;

    // workspace layout (16B aligned throughout)
    char* ws = (char*)d_ws;
    bf16* wQKV  = (bf16*)ws;  ws += (size_t)1536 * 512 * 2;   // packed
    bf16* wPROJ = (bf16*)ws;  ws += (size_t)512  * 512 * 2;
    bf16* wFC1  = (bf16*)ws;  ws += (size_t)2048 * 512 * 2;
    bf16* wFC2  = (bf16*)ws;  ws += (size_t)512 * 2048 * 2;
    bf16* hA    = (bf16*)ws;  ws += (size_t)NTOK * 512 * 2;   // 64 MB: h_ln -> o -> h2
    bf16* big   = (bf16*)ws;                                  // 256 MB: qkv -> fc1 out
    const size_t needed = 6291456ull + 67108864ull + 268435456ull;
    if (ws_size < needed) return;

    // weight packing (fp32 -> frag-order bf16 slabs)
    packb<<<384, 256, 0, stream>>>(qkv_w,  wQKV, 1536, 512);
    packb<<<128, 256, 0, stream>>>(proj_w, wPROJ, 512, 512);
    packb<<<512, 256, 0, stream>>>(fc1_w,  wFC1, 2048, 512);
    packb<<<512, 256, 0, stream>>>(fc2_w,  wFC2, 512, 2048);

    // LN1: x -> hA (bf16)
    ln_kernel<<<NTOK / 4, 256, 0, stream>>>(x, ln_g, ln_b, hA);
    // qkv = hA @ qkv_w^T  -> big
    gemmk64<0><<<dim3(12 * 512), 256, 0, stream>>>(
        hA, wQKV, NTOK, 1536, 512, 12, nullptr, nullptr, nullptr, big);
    // attention: big -> hA (o)
    attn_kernel<<<BQ, 256, 0, stream>>>(big, rpb, hA);
    // x1 = x + o @ proj_w^T + proj_b -> out (fp32)
    gemmk64<1><<<dim3(4 * 512), 256, 0, stream>>>(
        hA, wPROJ, NTOK, 512, 512, 4, proj_b, x, out, nullptr);
    // LN2: out -> hA (h2)
    ln_kernel<<<NTOK / 4, 256, 0, stream>>>(out, ln_g, ln_b, hA);
    // g = gelu(h2 @ fc1_w^T + fc1_b) -> big (bf16)
    gemmk64<2><<<dim3(16 * 512), 256, 0, stream>>>(
        hA, wFC1, NTOK, 2048, 512, 16, fc1_b, nullptr, nullptr, big);
    // out = x1 + g @ fc2_w^T + fc2_b (in-place residual read)
    gemmk64<1><<<dim3(4 * 512), 256, 0, stream>>>(
        big, wFC2, NTOK, 512, 2048, 4, fc2_b, out, out, nullptr);
}

// Round 13
// 849.935 us; speedup vs baseline: 2.7348x; 1.0330x over previous
//
#include <hip/hip_runtime.h>
#include <hip/hip_bf16.h>
#include <math.h>

// Problem constants
#define BQ   16384        // windows
#define CH   512
#define NH   8
#define HID  2048
#define NTOK (BQ*4)       // 65536 rows

using bf16 = __hip_bfloat16;
typedef __bf16 bf16x8 __attribute__((ext_vector_type(8)));
typedef float  f32x4  __attribute__((ext_vector_type(4)));

#define FENCE() asm volatile("" ::: "memory")

__device__ __forceinline__ void gload16(const void* g, void* l) {
    __builtin_amdgcn_global_load_lds(
        (const __attribute__((address_space(1))) void*)g,
        (__attribute__((address_space(3))) void*)l, 16, 0, 0);
}

// ---------------- weight pack: fp32 row-major [N][K] -> staged-order bf16 ----
// 16KB slab per (colblock cb of 256 rows-of-W, K-slice s of 32):
//   elem addr = (cb*NSk + s)*8192 + w*1024 + jj*512 + l*8    (w<8, jj<2, l<64)
//   content   = W[cb*256 + w*32 + jj*16 + (l>>2)][s*32 + ((l&3)^((l>>3)&3))*8 ..+8]
// (verified correct in round 8: absmax passed with this pack + the XOR reads)
__global__ __launch_bounds__(256) void packw(const float* __restrict__ Wsrc,
                                             bf16* __restrict__ out, int N, int K) {
    int q = blockIdx.x * 256 + threadIdx.x;      // 16B-chunk id
    int NSk = K >> 5;
    int total = (N >> 8) * NSk * 1024;
    if (q >= total) return;
    int l  = q & 63;
    int jj = (q >> 6) & 1;
    int w  = (q >> 7) & 7;
    int s  = (q >> 10) % NSk;
    int cb = q / (NSk * 1024);
    int row = cb * 256 + w * 32 + jj * 16 + (l >> 2);
    int k   = s * 32 + ((l & 3) ^ ((l >> 3) & 3)) * 8;
    const float* src = Wsrc + (size_t)row * K + k;
    float4 v0 = *(const float4*)src;
    float4 v1 = *(const float4*)(src + 4);
    __align__(16) bf16 t[8];
    t[0] = __float2bfloat16(v0.x); t[1] = __float2bfloat16(v0.y);
    t[2] = __float2bfloat16(v0.z); t[3] = __float2bfloat16(v0.w);
    t[4] = __float2bfloat16(v1.x); t[5] = __float2bfloat16(v1.y);
    t[6] = __float2bfloat16(v1.z); t[7] = __float2bfloat16(v1.w);
    *(uint4*)&out[(size_t)q * 8] = *(const uint4*)t;
}

// ---------------- LayerNorm (fp32 in, bf16 out), one wave per row ----------------
__global__ __launch_bounds__(256) void ln_kernel(const float* __restrict__ x,
                                                 const float* __restrict__ g,
                                                 const float* __restrict__ b,
                                                 bf16* __restrict__ out) {
    int row  = blockIdx.x * 4 + (threadIdx.x >> 6);
    int lane = threadIdx.x & 63;
    const float* xr = x + (size_t)row * CH;
    int c0 = lane * 8;
    float4 v0 = *(const float4*)&xr[c0];
    float4 v1 = *(const float4*)&xr[c0 + 4];
    float s  = v0.x + v0.y + v0.z + v0.w + v1.x + v1.y + v1.z + v1.w;
    float sq = v0.x*v0.x + v0.y*v0.y + v0.z*v0.z + v0.w*v0.w
             + v1.x*v1.x + v1.y*v1.y + v1.z*v1.z + v1.w*v1.w;
#pragma unroll
    for (int off = 32; off >= 1; off >>= 1) {
        s  += __shfl_xor(s,  off, 64);
        sq += __shfl_xor(sq, off, 64);
    }
    float mu  = s * (1.0f / CH);
    float var = sq * (1.0f / CH) - mu * mu;
    float rs  = rsqrtf(var + 1e-5f);
    float4 g0 = *(const float4*)&g[c0];
    float4 g1 = *(const float4*)&g[c0 + 4];
    float4 b0 = *(const float4*)&b[c0];
    float4 b1 = *(const float4*)&b[c0 + 4];
    __align__(16) bf16 t[8];
    t[0] = __float2bfloat16((v0.x - mu) * rs * g0.x + b0.x);
    t[1] = __float2bfloat16((v0.y - mu) * rs * g0.y + b0.y);
    t[2] = __float2bfloat16((v0.z - mu) * rs * g0.z + b0.z);
    t[3] = __float2bfloat16((v0.w - mu) * rs * g0.w + b0.w);
    t[4] = __float2bfloat16((v1.x - mu) * rs * g1.x + b1.x);
    t[5] = __float2bfloat16((v1.y - mu) * rs * g1.y + b1.y);
    t[6] = __float2bfloat16((v1.z - mu) * rs * g1.z + b1.z);
    t[7] = __float2bfloat16((v1.w - mu) * rs * g1.w + b1.w);
    *(uint4*)&out[(size_t)row * CH + c0] = *(const uint4*)t;
}

// ---------------- GEMM 256x256, faithful m201 8-phase template ------------------
// C[M,N] = A[M,K] * B[N,K]^T.  Ring-4 LDS of K-32 tiles (32KB: A16|B16).
// 8 waves (2M x 4N), wave tile 128x64.  Per tile t, 2 phases:
//  P0: { ds_read A(t) x8 + B-n01(t) x2 ; stageA(t+3) ; bar ; lgkm0 ;
//        prio1 16xMFMA(n01) prio0 ; bar }
//  P1: { ds_read B-n23(t) x2 ; stageB(t+3) ; bar ; lgkm0 ;
//        prio1 16xMFMA(n23) prio0 ; vmcnt(8) ; bar }
// KEY vs failed ports: reads are THIS phase's operands issued BEFORE the
// leading barrier (latency absorbed by barrier convergence; lgkm0 then cheap);
// full lgkmcnt(0) not counted; vmcnt once per tile at tile END (retires t+1,
// leaves t+2/t+3's 8 loads in flight - never 0); NO sched_barrier (m141).
// WAR: stage(t+3) writes slot (t-1)&3 whose readers finished >=1 barrier ago.
// Tail peel: vmcnt 8 -> 4 -> 0 as staging stops.  launch_bounds(512,2)
// REQUIRED (round 5: without it 64-VGPR alloc -> acc spills -> 11GB scratch).
template<int EPI>
__global__ __launch_bounds__(512, 2)
void gemm8p(const bf16* __restrict__ A, const bf16* __restrict__ Bp,
            int M, int N, int K, int nbx,
            const float* __restrict__ bias,
            const float* resid, float* outF, bf16* __restrict__ outB) {
    __shared__ __align__(16) char lds[131072];
    const int tid  = threadIdx.x;
    const int w    = tid >> 6;     // wave 0..7
    const int lane = tid & 63;

    // bijective XCD swizzle (gridDim.x % 8 == 0 for all our shapes)
    const int nb  = gridDim.x;
    const int id  = blockIdx.x;
    const int swz = (id & 7) * (nb >> 3) + (id >> 3);
    const int bx  = swz % nbx, by = swz / nbx;
    const int bm = by * 256, bn = bx * 256;
    const int wr = w >> 2;         // 0..1  (M half)
    const int wc = w & 3;          // 0..3  (N quarter)
    const int NSk = K >> 5;        // K/32 tiles (16 or 64)

    // A staging (strided rows, pre-swizzled k-part)
    const int rl  = lane >> 2;
    const int kpe = ((lane & 3) ^ ((lane >> 3) & 3)) * 8;
    const bf16* gA0 = A + (size_t)(bm + w * 32 + rl) * K + kpe;
    const bf16* gA1 = gA0 + (size_t)16 * K;
    // B staging (packed, contiguous 1KB per load)
    const bf16* gB = Bp + (size_t)(bn >> 8) * NSk * 8192 + w * 1024 + lane * 8;

    // fragment read offsets (bytes) within a slot; same XOR on the read side
    const int kslot = ((lane >> 4) ^ ((lane >> 1) & 3));
    const int aoff = (wr * 128 + (lane & 15)) * 64 + kslot * 16;
    const int boff = 16384 + (wc * 64 + (lane & 15)) * 64 + kslot * 16;

    f32x4 acc[8][4] = {};
    bf16x8 av[8], bl[2], bh[2];

    auto stageA = [&](int t) {
        char* base = (char*)lds + (t & 3) * 32768;
        gload16(gA0 + (size_t)t * 32, base + w * 2048);
        gload16(gA1 + (size_t)t * 32, base + w * 2048 + 1024);
    };
    auto stageB = [&](int t) {
        char* base = (char*)lds + (t & 3) * 32768 + 16384;
        gload16(gB + (size_t)t * 8192,       base + w * 2048);
        gload16(gB + (size_t)t * 8192 + 512, base + w * 2048 + 1024);
    };

#define SBAR()  __builtin_amdgcn_s_barrier()
#define LGKM0() asm volatile("s_waitcnt lgkmcnt(0)" ::: "memory")
#define WAITV(n) asm volatile("s_waitcnt vmcnt(" #n ")" ::: "memory")

#define PH0(T, DOSTAGE) {                                                    \
    const char* _b = (const char*)lds + (size_t)((T) & 3) * 32768;           \
    _Pragma("unroll") for (int _m = 0; _m < 8; ++_m)                         \
        av[_m] = *(const bf16x8*)(_b + aoff + _m * 1024);                    \
    bl[0] = *(const bf16x8*)(_b + boff);                                     \
    bl[1] = *(const bf16x8*)(_b + boff + 1024);                              \
    if (DOSTAGE) stageA((T) + 3);                                            \
    SBAR(); LGKM0();                                                         \
    __builtin_amdgcn_s_setprio(1);                                           \
    _Pragma("unroll") for (int _m = 0; _m < 8; ++_m) {                       \
        acc[_m][0] = __builtin_amdgcn_mfma_f32_16x16x32_bf16(av[_m], bl[0], acc[_m][0], 0, 0, 0); \
        acc[_m][1] = __builtin_amdgcn_mfma_f32_16x16x32_bf16(av[_m], bl[1], acc[_m][1], 0, 0, 0); } \
    __builtin_amdgcn_s_setprio(0);                                           \
    SBAR(); }

#define PH1(T, DOSTAGE, VMW) {                                               \
    const char* _b = (const char*)lds + (size_t)((T) & 3) * 32768;           \
    bh[0] = *(const bf16x8*)(_b + boff + 2048);                              \
    bh[1] = *(const bf16x8*)(_b + boff + 3072);                              \
    if (DOSTAGE) stageB((T) + 3);                                            \
    SBAR(); LGKM0();                                                         \
    __builtin_amdgcn_s_setprio(1);                                           \
    _Pragma("unroll") for (int _m = 0; _m < 8; ++_m) {                       \
        acc[_m][2] = __builtin_amdgcn_mfma_f32_16x16x32_bf16(av[_m], bh[0], acc[_m][2], 0, 0, 0); \
        acc[_m][3] = __builtin_amdgcn_mfma_f32_16x16x32_bf16(av[_m], bh[1], acc[_m][3], 0, 0, 0); } \
    __builtin_amdgcn_s_setprio(0);                                           \
    VMW;                                                                     \
    SBAR(); }

    // prologue: fill ring tiles 0..2 (12 loads); tile 0 landed before reads
    stageA(0); stageB(0); stageA(1); stageB(1); stageA(2); stageB(2);
    WAITV(8); SBAR();

    // main loop: uniform vmcnt(8) while staging continues
    for (int t = 0; t < NSk - 3; ++t) {
        PH0(t, true);
        PH1(t, true, WAITV(8));
    }
    // tail peel: no staging; vmcnt retires remaining tiles 4 -> 0
    PH0(NSk - 3, false);
    PH1(NSk - 3, false, WAITV(4));
    PH0(NSk - 2, false);
    PH1(NSk - 2, false, WAITV(0));
    PH0(NSk - 1, false);
    {   // final P1: no vmcnt, no trailing barrier needed
        const char* _b = (const char*)lds + (size_t)((NSk - 1) & 3) * 32768;
        bh[0] = *(const bf16x8*)(_b + boff + 2048);
        bh[1] = *(const bf16x8*)(_b + boff + 3072);
        LGKM0();
#pragma unroll
        for (int m = 0; m < 8; ++m) {
            acc[m][2] = __builtin_amdgcn_mfma_f32_16x16x32_bf16(av[m], bh[0], acc[m][2], 0, 0, 0);
            acc[m][3] = __builtin_amdgcn_mfma_f32_16x16x32_bf16(av[m], bh[1], acc[m][3], 0, 0, 0);
        }
    }
#undef PH0
#undef PH1
#undef SBAR
#undef LGKM0
#undef WAITV

    // epilogue: frag (m,n): row = wr*128 + m*16 + (lane>>4)*4 + r, col = wc*64 + n*16 + (lane&15)
    const int erow0 = bm + wr * 128 + (lane >> 4) * 4;
    const int ecol0 = bn + wc * 64 + (lane & 15);
#pragma unroll
    for (int m = 0; m < 8; ++m) {
#pragma unroll
        for (int n = 0; n < 4; ++n) {
            int col = ecol0 + n * 16;
#pragma unroll
            for (int r = 0; r < 4; ++r) {
                int row = erow0 + m * 16 + r;
                size_t idx = (size_t)row * N + col;
                float v = acc[m][n][r];
                if (EPI == 0) {
                    outB[idx] = __float2bfloat16(v);
                } else if (EPI == 1) {
                    outF[idx] = v + bias[col] + resid[idx];
                } else {
                    // tanh-form GELU (|err| vs exact erf-GELU ~3e-4 << bf16 ulp)
                    float t = v + bias[col];
                    float u = 0.7978845608f * t * (1.0f + 0.044715f * t * t);
                    float e = __expf(2.0f * u);
                    float th = 1.0f - 2.0f / (e + 1.0f);   // inf-safe
                    outB[idx] = __float2bfloat16(0.5f * t * (1.0f + th));
                }
            }
        }
    }
}

// ---------------- windowed attention: one block per window ----------------
__global__ __launch_bounds__(256)
void attn_kernel(const bf16* __restrict__ qkv, const float* __restrict__ rpb,
                 bf16* __restrict__ o) {
    __shared__ __align__(16) bf16 sT[4 * 1536];
    __shared__ float sS[NH][4][4];
    __shared__ float sP[NH][4][4];
    int b   = blockIdx.x;
    int tid = threadIdx.x;
    const bf16* src = qkv + (size_t)b * (4 * 1536);
#pragma unroll
    for (int it = 0; it < 3; ++it) {
        int e = (it * 256 + tid) * 8;
        *(uint4*)&sT[e] = *(const uint4*)&src[e];
    }
    __syncthreads();
    if (tid < 128) {
        int h = tid >> 4, i = (tid >> 2) & 3, j = tid & 3;
        const bf16* q = &sT[i * 1536 + h * 64];
        const bf16* k = &sT[j * 1536 + 512 + h * 64];
        float acc = 0.f;
#pragma unroll
        for (int d = 0; d < 64; ++d)
            acc += __bfloat162float(q[d]) * __bfloat162float(k[d]);
        int rel = (((i >> 1) - (j >> 1)) + 1) * 3 + (((i & 1) - (j & 1)) + 1);
        sS[h][i][j] = acc * 0.125f + rpb[rel * NH + h];
    }
    __syncthreads();
    if (tid < 32) {
        int h = tid >> 2, i = tid & 3;
        float s0 = sS[h][i][0], s1 = sS[h][i][1], s2 = sS[h][i][2], s3 = sS[h][i][3];
        float mx = fmaxf(fmaxf(s0, s1), fmaxf(s2, s3));
        float e0 = expf(s0 - mx), e1 = expf(s1 - mx), e2 = expf(s2 - mx), e3 = expf(s3 - mx);
        float inv = 1.f / (e0 + e1 + e2 + e3);
        sP[h][i][0] = e0 * inv; sP[h][i][1] = e1 * inv;
        sP[h][i][2] = e2 * inv; sP[h][i][3] = e3 * inv;
    }
    __syncthreads();
    {
        int h = tid >> 5, tl = tid & 31;
        int d = tl * 2;
        const bf16* v = &sT[1024 + h * 64 + d];
#pragma unroll
        for (int i = 0; i < 4; ++i) {
            float p0 = sP[h][i][0], p1 = sP[h][i][1], p2 = sP[h][i][2], p3 = sP[h][i][3];
            float o0 = p0 * __bfloat162float(v[0])        + p1 * __bfloat162float(v[1536])
                     + p2 * __bfloat162float(v[2 * 1536]) + p3 * __bfloat162float(v[3 * 1536]);
            float o1 = p0 * __bfloat162float(v[1])            + p1 * __bfloat162float(v[1536 + 1])
                     + p2 * __bfloat162float(v[2 * 1536 + 1]) + p3 * __bfloat162float(v[3 * 1536 + 1]);
            __hip_bfloat162 pr;
            pr.x = __float2bfloat16(o0);
            pr.y = __float2bfloat16(o1);
            *(__hip_bfloat162*)&o[(size_t)(b * 4 + i) * CH + h * 64 + d] = pr;
        }
    }
}

extern "C" void kernel_launch(void* const* d_in, const int* in_sizes, int n_in,
                              void* d_out, int out_size, void* d_ws, size_t ws_size,
                              hipStream_t stream) {
    const float* x      = (const float*)d_in[0];
    const float* ln_g   = (const float*)d_in[1];
    const float* ln_b   = (const float*)d_in[2];
    const float* qkv_w  = (const float*)d_in[3];
    const float* proj_w = (const float*)d_in[4];
    const float* proj_b = (const float*)d_in[5];
    const float* rpb    = (const float*)d_in[6];
    const float* fc1_w  = (const float*)d_in[7];
    const float* fc1_b  = (const float*)d_in[8];
    const float* fc2_w  = (const float*)d_in[9];
    const float* fc2_b  = (const float*)d_in[10];
    float* out = (float*)d_out;

    // workspace layout (16B aligned throughout)
    char* ws = (char*)d_ws;
    bf16* wQKV  = (bf16*)ws;  ws += (size_t)1536 * 512 * 2;   // packed
    bf16* wPROJ = (bf16*)ws;  ws += (size_t)512  * 512 * 2;
    bf16* wFC1  = (bf16*)ws;  ws += (size_t)2048 * 512 * 2;
    bf16* wFC2  = (bf16*)ws;  ws += (size_t)512 * 2048 * 2;
    bf16* hA    = (bf16*)ws;  ws += (size_t)NTOK * 512 * 2;   // 64 MB: h_ln -> o -> h2
    bf16* big   = (bf16*)ws;                                  // 256 MB: qkv -> fc1 out
    const size_t needed = 6291456ull + 67108864ull + 268435456ull;
    if (ws_size < needed) return;

    // weight packing (fp32 -> staged-order bf16, 256-row col-blocks)
    packw<<<384, 256, 0, stream>>>(qkv_w,  wQKV, 1536, 512);
    packw<<<128, 256, 0, stream>>>(proj_w, wPROJ, 512, 512);
    packw<<<512, 256, 0, stream>>>(fc1_w,  wFC1, 2048, 512);
    packw<<<512, 256, 0, stream>>>(fc2_w,  wFC2, 512, 2048);

    // LN1: x -> hA (bf16)
    ln_kernel<<<NTOK / 4, 256, 0, stream>>>(x, ln_g, ln_b, hA);
    // qkv = hA @ qkv_w^T  -> big
    gemm8p<0><<<dim3(6 * 256), 512, 0, stream>>>(
        hA, wQKV, NTOK, 1536, 512, 6, nullptr, nullptr, nullptr, big);
    // attention: big -> hA (o)
    attn_kernel<<<BQ, 256, 0, stream>>>(big, rpb, hA);
    // x1 = x + o @ proj_w^T + proj_b -> out (fp32)
    gemm8p<1><<<dim3(2 * 256), 512, 0, stream>>>(
        hA, wPROJ, NTOK, 512, 512, 2, proj_b, x, out, nullptr);
    // LN2: out -> hA (h2)
    ln_kernel<<<NTOK / 4, 256, 0, stream>>>(out, ln_g, ln_b, hA);
    // g = gelu(h2 @ fc1_w^T + fc1_b) -> big (bf16)
    gemm8p<2><<<dim3(8 * 256), 512, 0, stream>>>(
        hA, wFC1, NTOK, 2048, 512, 8, fc1_b, nullptr, nullptr, big);
    // out = x1 + g @ fc2_w^T + fc2_b (in-place residual read)
    gemm8p<1><<<dim3(2 * 256), 512, 0, stream>>>(
        big, wFC2, NTOK, 512, 2048, 2, fc2_b, out, out, nullptr);
}